// Round 1
// baseline (951.749 us; speedup 1.0000x reference)
//
#include <hip/hip_runtime.h>
#include <math.h>

// GFlowNet actor rollout on MI355X.
// B=4096 rollouts, NTOT=100000 nodes, D=32 out-degree, H=64 hidden, T=8 (9 steps).
// One 64-lane wave per rollout; lane j owns hidden[j]. 4 waves / 256-thread block.
// Memory-bound on the action_keys gather (8KB per rollout-step, ~295MB total).

namespace {
constexpr int Bx   = 4096;
constexpr int Dx   = 32;
constexpr int Hx   = 64;
constexpr int Tx   = 8;
constexpr float NEGV   = -1e9f;
constexpr float LN_EPS = 1e-5f;
constexpr float MIN_T  = 1e-5f;
} // namespace

__device__ __forceinline__ float wave_sum64(float v) {
#pragma unroll
  for (int m = 32; m >= 1; m >>= 1) v += __shfl_xor(v, m);
  return v;
}
__device__ __forceinline__ float wave_max64(float v) {
#pragma unroll
  for (int m = 32; m >= 1; m >>= 1) v = fmaxf(v, __shfl_xor(v, m));
  return v;
}

__global__ __launch_bounds__(256, 4) void gflow_rollout(
    const float* __restrict__ q_tokens,      // [B,H]
    const int*   __restrict__ nbr_node,      // [NTOT,D]
    const int*   __restrict__ start_nodes,   // [B]
    const int*   __restrict__ edge_valid,    // [NTOT,D] (bool as int32)
    const float* __restrict__ action_keys,   // [NTOT,D,H]
    const float* __restrict__ W_init,        // [H,H]
    const float* __restrict__ W_h,           // [H,H]
    const float* __restrict__ W_k,           // [H,H]
    const float* __restrict__ ln_gamma,      // [H+2]
    const float* __restrict__ ln_beta,       // [H+2]
    const float* __restrict__ stop_w,        // [H+2]
    const float* __restrict__ stop_b,        // [1]
    const float* __restrict__ temperature,   // [1]
    float* __restrict__ out)                 // [B*9 | B | B*9 | B] all as f32
{
  __shared__ float Wh_s[Hx * Hx];   // 16KB
  __shared__ float Wk_s[Hx * Hx];   // 16KB
  __shared__ float h_s[4][Hx];      // per-wave hidden
  __shared__ float sel_s[4][Hx];    // per-wave q (init) / selected key (steps)

  const int tid   = threadIdx.x;
  const int lane  = tid & 63;
  const int wslot = tid >> 6;
  const int b     = blockIdx.x * 4 + wslot;

  // ---- stage W_h, W_k into LDS (whole block cooperates) ----
  {
    const float4* sh = (const float4*)W_h;
    const float4* sk = (const float4*)W_k;
    float4* dh = (float4*)Wh_s;
    float4* dk = (float4*)Wk_s;
#pragma unroll
    for (int i = 0; i < (Hx * Hx / 4) / 256; ++i) {
      dh[tid + i * 256] = sh[tid + i * 256];
      dk[tid + i * 256] = sk[tid + i * 256];
    }
  }

  // ---- per-lane constants ----
  const float g_j  = ln_gamma[lane];
  const float be_j = ln_beta[lane];
  const float w_j  = stop_w[lane];
  const float g64 = ln_gamma[64], g65 = ln_gamma[65];
  const float b64 = ln_beta[64],  b65 = ln_beta[65];
  const float w64 = stop_w[64],   w65 = stop_w[65];
  const float sb  = stop_b[0];
  const float tcl = fmaxf(temperature[0], MIN_T);

  // ---- hidden0 = tanh(q @ W_init) ----
  sel_s[wslot][lane] = q_tokens[b * Hx + lane];
  __syncthreads();  // also covers W staging
  float acc0 = 0.f;
#pragma unroll 16
  for (int i = 0; i < Hx; ++i)
    acc0 = fmaf(sel_s[wslot][i], W_init[i * Hx + lane], acc0);
  float hid = tanhf(acc0);
  h_s[wslot][lane] = hid;
  __syncthreads();

  int   cur      = start_nodes[b];
  bool  stopped  = false;
  float lp_total = 0.f;
  int   nmoves   = 0;

  const int d    = lane & 31;
  const int half = lane >> 5;

  for (int t = 0; t <= Tx; ++t) {
    // ---- gather keys[curr]: lane covers half-row (d, half*32..+31) ----
    float4 kq[8];
    if (!stopped) {
      const float4* kp =
          (const float4*)(action_keys + ((size_t)cur * Dx + d) * Hx + half * 32);
#pragma unroll
      for (int c = 0; c < 8; ++c) kq[c] = kp[c];
    } else {
#pragma unroll
      for (int c = 0; c < 8; ++c) kq[c] = make_float4(0.f, 0.f, 0.f, 0.f);
    }

    // ---- scores[d] = <hidden, keys[d]> ----
    float part = 0.f;
    {
      const float* hp = &h_s[wslot][half * 32];
#pragma unroll
      for (int c = 0; c < 8; ++c) {
        float4 hv = *(const float4*)(hp + 4 * c);
        part = fmaf(kq[c].x, hv.x, part);
        part = fmaf(kq[c].y, hv.y, part);
        part = fmaf(kq[c].z, hv.z, part);
        part = fmaf(kq[c].w, hv.w, part);
      }
    }
    const float score = part + __shfl_xor(part, 32);

    // ---- validity ----
    const bool horizon = (t == Tx);
    int evi = 0;
    if (!stopped && !horizon) evi = edge_valid[(size_t)cur * Dx + d];
    const bool validd = (evi != 0);
    const unsigned long long vmask = __ballot(validd);
    const bool has_edge = (vmask != 0ULL);

    // ---- layernorm(concat(hidden, t/T, has_edge)) . stop_w + stop_b ----
    const float sf = (float)t / (float)Tx;
    const float he = has_edge ? 1.0f : 0.0f;
    float xs = hid;
    if (lane == 0) xs += sf;
    if (lane == 1) xs += he;
    const float mu = wave_sum64(xs) / 66.0f;
    const float dcj = hid - mu;
    float vs = dcj * dcj;
    if (lane == 0) { float dd = sf - mu; vs += dd * dd; }
    if (lane == 1) { float dd = he - mu; vs += dd * dd; }
    const float var  = wave_sum64(vs) / 66.0f;
    const float rstd = rsqrtf(var + LN_EPS);
    float contrib = (dcj * rstd * g_j + be_j) * w_j;
    if (lane == 0) contrib += ((sf - mu) * rstd * g64 + b64) * w64;
    if (lane == 1) contrib += ((he - mu) * rstd * g65 + b65) * w65;
    const float stop_logit = wave_sum64(contrib) + sb;

    // ---- logits (lanes 0..31 edges, lane 32 stop), softmax, argmax ----
    float lg;
    if (lane < 32)       lg = (validd ? score : NEGV) / tcl;
    else if (lane == 32) lg = stop_logit / tcl;
    else                 lg = -INFINITY;
    const float mx = wave_max64(lg);
    const float ex = (lane <= 32) ? expf(lg - mx) : 0.f;
    const float se = wave_sum64(ex);

    int action;
    if (stopped) {
      action = Dx;
    } else {
      unsigned long long am = __ballot(lg == mx);
      action = __ffsll((unsigned long long)am) - 1;
    }
    const float lga = __shfl(lg, action & 63);
    const float lp  = stopped ? 0.f : (lga - mx - logf(se));

    const bool chose_stop = (action == Dx);
    const int  a    = min(action, Dx - 1);
    const int  tail = nbr_node[(size_t)cur * Dx + a];

    // ---- selected key into LDS (broadcast source for matvec) ----
    if (!chose_stop) {
      sel_s[wslot][lane] = action_keys[((size_t)cur * Dx + a) * Hx + lane];
    }
    __syncthreads();  // A: sel write -> matvec reads

    // ---- new_hidden = tanh(hidden @ W_h + sel @ W_k) ----
    float a1 = 0.f, a2 = 0.f;
#pragma unroll 8
    for (int i = 0; i < Hx; i += 4) {
      float4 hv = *(const float4*)&h_s[wslot][i];
      float4 sv = *(const float4*)&sel_s[wslot][i];
      a1 = fmaf(hv.x, Wh_s[(i + 0) * Hx + lane], a1);
      a2 = fmaf(sv.x, Wk_s[(i + 0) * Hx + lane], a2);
      a1 = fmaf(hv.y, Wh_s[(i + 1) * Hx + lane], a1);
      a2 = fmaf(sv.y, Wk_s[(i + 1) * Hx + lane], a2);
      a1 = fmaf(hv.z, Wh_s[(i + 2) * Hx + lane], a1);
      a2 = fmaf(sv.z, Wk_s[(i + 2) * Hx + lane], a2);
      a1 = fmaf(hv.w, Wh_s[(i + 3) * Hx + lane], a1);
      a2 = fmaf(sv.w, Wk_s[(i + 3) * Hx + lane], a2);
    }
    const float nh = tanhf(a1 + a2);
    __syncthreads();  // B: h reads done before overwrite

    if (!chose_stop) {
      hid = nh;
      h_s[wslot][lane] = hid;
    }
    __syncthreads();  // C: h write -> next step's reads

    const int rec = chose_stop ? -1 : (cur * Dx + a);
    if (!chose_stop) { cur = tail; nmoves++; }
    lp_total += lp;
    stopped = stopped || chose_stop;

    if (lane == 0) {
      out[b * (Tx + 1) + t] = (float)rec;                       // actions_seq
      out[Bx * (Tx + 1) + Bx + b * (Tx + 1) + t] = lp;          // log_pf_steps
    }
  }

  if (lane == 0) {
    out[Bx * (Tx + 1) + b] = lp_total;                          // log_pf_total
    out[Bx * (Tx + 1) + Bx + Bx * (Tx + 1) + b] = (float)nmoves; // num_moves
  }
}

extern "C" void kernel_launch(void* const* d_in, const int* in_sizes, int n_in,
                              void* d_out, int out_size, void* d_ws, size_t ws_size,
                              hipStream_t stream) {
  const float* q_tokens    = (const float*)d_in[0];
  const int*   nbr_node    = (const int*)d_in[1];
  const int*   start_nodes = (const int*)d_in[2];
  const int*   edge_valid  = (const int*)d_in[3];
  const float* action_keys = (const float*)d_in[4];
  const float* W_init      = (const float*)d_in[5];
  const float* W_h         = (const float*)d_in[6];
  const float* W_k         = (const float*)d_in[7];
  const float* ln_gamma    = (const float*)d_in[8];
  const float* ln_beta     = (const float*)d_in[9];
  const float* stop_w      = (const float*)d_in[10];
  const float* stop_b      = (const float*)d_in[11];
  const float* temperature = (const float*)d_in[12];
  float* out = (float*)d_out;

  dim3 grid(Bx / 4);
  dim3 block(256);
  gflow_rollout<<<grid, block, 0, stream>>>(
      q_tokens, nbr_node, start_nodes, edge_valid, action_keys,
      W_init, W_h, W_k, ln_gamma, ln_beta, stop_w, stop_b, temperature, out);
}

// Round 2
// 941.250 us; speedup vs baseline: 1.0112x; 1.0112x over previous
//
#include <hip/hip_runtime.h>
#include <math.h>

// GFlowNet actor rollout on MI355X — round 2.
// One 64-lane wave per rollout, 4 waves/block, no in-loop barriers.
// Broadcasts via v_readlane (VALU) instead of LDS; nbr+edge_valid fused into
// one load issued with the keys gather; next-step gather issued before the
// matvec so HBM latency overlaps compute; waves retire at stop.

namespace {
constexpr int Bx = 4096;
constexpr int Dx = 32;
constexpr int Hx = 64;
constexpr int Tx = 8;
constexpr float NEGV   = -1e9f;
constexpr float LN_EPS = 1e-5f;
constexpr float MIN_T  = 1e-5f;
} // namespace

__device__ __forceinline__ float wsum(float v) {
#pragma unroll
  for (int m = 32; m >= 1; m >>= 1) v += __shfl_xor(v, m);
  return v;
}
__device__ __forceinline__ float wmax(float v) {
#pragma unroll
  for (int m = 32; m >= 1; m >>= 1) v = fmaxf(v, __shfl_xor(v, m));
  return v;
}
// wave-uniform broadcast of lane i's value (VALU v_readlane; i is a literal
// after full unroll). Avoids the DS pipe and any LDS ordering assumptions.
__device__ __forceinline__ float lanebc(float v, int i) {
  return __int_as_float(__builtin_amdgcn_readlane(__float_as_int(v), i));
}

__global__ __launch_bounds__(256, 4) void gflow_rollout(
    const float* __restrict__ q_tokens,      // [B,H]
    const int*   __restrict__ nbr_node,      // [NTOT,D]
    const int*   __restrict__ start_nodes,   // [B]
    const int*   __restrict__ edge_valid,    // [NTOT,D]
    const float* __restrict__ action_keys,   // [NTOT,D,H]
    const float* __restrict__ W_init,        // [H,H]
    const float* __restrict__ W_h,           // [H,H]
    const float* __restrict__ W_k,           // [H,H]
    const float* __restrict__ ln_gamma,      // [H+2]
    const float* __restrict__ ln_beta,       // [H+2]
    const float* __restrict__ stop_w,        // [H+2]
    const float* __restrict__ stop_b,        // [1]
    const float* __restrict__ temperature,   // [1]
    float* __restrict__ out)                 // [B*9 | B | B*9 | B] as f32
{
  __shared__ float Wh_s[Hx * Hx];   // 16KB
  __shared__ float Wk_s[Hx * Hx];   // 16KB

  const int tid   = threadIdx.x;
  const int lane  = tid & 63;
  const int wslot = tid >> 6;
  const int b     = blockIdx.x * 4 + wslot;
  const int d     = lane & 31;
  const int half  = lane >> 5;

  int cur = start_nodes[b];

  // ---- issue t=0 gather immediately (overlaps W staging + init matvec) ----
  float kf[32];                 // this lane's half-row of keys (32 floats)
  {
    const float4* kp =
        (const float4*)(action_keys + ((size_t)cur * Dx + d) * Hx + half * 32);
#pragma unroll
    for (int c = 0; c < 8; ++c) ((float4*)kf)[c] = kp[c];
  }
  // fused aux row: lanes 0..31 -> edge_valid[cur][d], lanes 32..63 -> nbr[cur][d]
  const int* evn_base = (lane < Dx) ? edge_valid : nbr_node;
  int evnb = evn_base[(size_t)cur * Dx + d];

  // ---- stage W_h, W_k into LDS (whole block) ----
  {
    const float4* sh = (const float4*)W_h;
    const float4* sk = (const float4*)W_k;
    float4* dh = (float4*)Wh_s;
    float4* dk = (float4*)Wk_s;
#pragma unroll
    for (int i = 0; i < 4; ++i) {
      dh[tid + i * 256] = sh[tid + i * 256];
      dk[tid + i * 256] = sk[tid + i * 256];
    }
  }

  // ---- per-lane constants ----
  const float g_j  = ln_gamma[lane];
  const float be_j = ln_beta[lane];
  const float w_j  = stop_w[lane];
  const float g64 = ln_gamma[64], g65 = ln_gamma[65];
  const float b64 = ln_beta[64],  b65 = ln_beta[65];
  const float w64 = stop_w[64],   w65 = stop_w[65];
  const float sb  = stop_b[0];
  const float tcl = fmaxf(temperature[0], MIN_T);

  // ---- hidden0 = tanh(q @ W_init)  (global W_init, coalesced, L2-hot) ----
  float hid;
  {
    const float qv = q_tokens[b * Hx + lane];
    float acc0 = 0.f;
#pragma unroll
    for (int i = 0; i < Hx; ++i)
      acc0 = fmaf(lanebc(qv, i), W_init[i * Hx + lane], acc0);
    hid = tanhf(acc0);
  }

  __syncthreads();  // the ONLY barrier: W_h/W_k staged before first matvec

  float lp_total = 0.f;
  int   nmoves   = 0;
  int   tstop    = Tx;  // loop always breaks via chose_stop by t=Tx

  float* out_act = out + (size_t)b * (Tx + 1);
  float* out_lps = out + (size_t)Bx * (Tx + 1) + Bx + (size_t)b * (Tx + 1);

  for (int t = 0; t <= Tx; ++t) {
    // ---- scores[d] = <hidden, keys[d]> (skip at horizon: fully masked) ----
    float score = 0.f;
    if (t < Tx) {
      float part = 0.f;
#pragma unroll
      for (int i = 0; i < 32; ++i) {
        const float hlo = lanebc(hid, i);
        const float hhi = lanebc(hid, i + 32);
        const float hv  = half ? hhi : hlo;
        part = fmaf(kf[i], hv, part);
      }
      score = part + __shfl_xor(part, 32);
    }

    const bool validd = (lane < Dx) && (evnb != 0) && (t < Tx);
    const unsigned long long vm = __ballot(validd);
    const bool has_edge = (vm != 0ULL);

    // ---- layernorm(concat(hidden, t/T, has_edge)) . stop_w + stop_b ----
    const float sf = (float)t / (float)Tx;
    const float he = has_edge ? 1.0f : 0.0f;
    float xs = hid;
    if (lane == 0) xs += sf;
    if (lane == 1) xs += he;
    const float mu  = wsum(xs) / 66.0f;
    const float dcj = hid - mu;
    float vs = dcj * dcj;
    if (lane == 0) { const float dd = sf - mu; vs += dd * dd; }
    if (lane == 1) { const float dd = he - mu; vs += dd * dd; }
    const float var  = wsum(vs) / 66.0f;
    const float rstd = rsqrtf(var + LN_EPS);
    float contrib = (dcj * rstd * g_j + be_j) * w_j;
    if (lane == 0) contrib += ((sf - mu) * rstd * g64 + b64) * w64;
    if (lane == 1) contrib += ((he - mu) * rstd * g65 + b65) * w65;
    const float stop_logit = wsum(contrib) + sb;

    // ---- logits / softmax / argmax (first-max = jnp.argmax semantics) ----
    float lg;
    if (lane < Dx)       lg = (validd ? score : NEGV) / tcl;
    else if (lane == Dx) lg = stop_logit / tcl;
    else                 lg = -INFINITY;
    const float mx = wmax(lg);
    const float ex = (lane <= Dx) ? expf(lg - mx) : 0.f;
    const float se = wsum(ex);
    const unsigned long long am = __ballot(lg == mx);
    const int   action = __ffsll(am) - 1;
    const float lga    = __shfl(lg, action);
    const float lp     = lga - mx - logf(se);

    const bool chose_stop = (action == Dx);
    const int  a = min(action, Dx - 1);

    if (lane == 0) {
      out_act[t] = chose_stop ? -1.0f : (float)(cur * Dx + a);
      out_lps[t] = lp;
    }
    lp_total += lp;

    if (chose_stop) { tstop = t; break; }
    nmoves++;

    // ---- selected key row (256B, L1-hot: subset of the 8KB just gathered) ----
    const float selv = action_keys[((size_t)cur * Dx + a) * Hx + lane];

    // ---- advance; issue NEXT gather before the matvec (latency overlap) ----
    cur = __shfl(evnb, Dx + a);   // nbr row rode along with the gather
    if (t + 1 < Tx) {
      const float4* kp =
          (const float4*)(action_keys + ((size_t)cur * Dx + d) * Hx + half * 32);
#pragma unroll
      for (int c = 0; c < 8; ++c) ((float4*)kf)[c] = kp[c];
      evnb = evn_base[(size_t)cur * Dx + d];
    }

    // ---- new_hidden = tanh(hidden @ W_h + sel @ W_k) ----
    float a1 = 0.f, a2 = 0.f;
#pragma unroll
    for (int i = 0; i < Hx; ++i) {
      a1 = fmaf(lanebc(hid,  i), Wh_s[i * Hx + lane], a1);
      a2 = fmaf(lanebc(selv, i), Wk_s[i * Hx + lane], a2);
    }
    hid = tanhf(a1 + a2);
  }

  // ---- epilogue: fill post-stop steps, totals ----
  if (lane == 0) {
    for (int t = tstop + 1; t <= Tx; ++t) { out_act[t] = -1.0f; out_lps[t] = 0.f; }
    out[(size_t)Bx * (Tx + 1) + b] = lp_total;                            // log_pf_total
    out[(size_t)Bx * (Tx + 1) + Bx + (size_t)Bx * (Tx + 1) + b] = (float)nmoves; // num_moves
  }
}

extern "C" void kernel_launch(void* const* d_in, const int* in_sizes, int n_in,
                              void* d_out, int out_size, void* d_ws, size_t ws_size,
                              hipStream_t stream) {
  const float* q_tokens    = (const float*)d_in[0];
  const int*   nbr_node    = (const int*)d_in[1];
  const int*   start_nodes = (const int*)d_in[2];
  const int*   edge_valid  = (const int*)d_in[3];
  const float* action_keys = (const float*)d_in[4];
  const float* W_init      = (const float*)d_in[5];
  const float* W_h         = (const float*)d_in[6];
  const float* W_k         = (const float*)d_in[7];
  const float* ln_gamma    = (const float*)d_in[8];
  const float* ln_beta     = (const float*)d_in[9];
  const float* stop_w      = (const float*)d_in[10];
  const float* stop_b      = (const float*)d_in[11];
  const float* temperature = (const float*)d_in[12];
  float* out = (float*)d_out;

  gflow_rollout<<<dim3(Bx / 4), dim3(256), 0, stream>>>(
      q_tokens, nbr_node, start_nodes, edge_valid, action_keys,
      W_init, W_h, W_k, ln_gamma, ln_beta, stop_w, stop_b, temperature, out);
}